// Round 5
// baseline (3986.436 us; speedup 1.0000x reference)
//
#include <hip/hip_runtime.h>

// Problem constants (fixed by setup_inputs). All float data is FLOAT32:
// reference dtypes are f32 (inputs) and int32/f32 (outputs); harness passes
// them through as float* (the "(bf16)" in its log is a comparison floor, not
// a buffer dtype — established by round-0/1/4 failure-signature forensics).
#define SS 4
#define BB 256
#define PP 32768
#define DD 256
#define QQ 1024          // SS*BB
#define NN 131072        // SS*PP candidate rows
#define KTOP 10
#define QG 32            // queries per block
#define NCHUNK 16        // n-chunks
#define CHROWS 8192      // rows per chunk (NN/NCHUNK)

typedef __attribute__((ext_vector_type(4))) float f32x4;

static __device__ __forceinline__ unsigned long long pack_sg(float sc, int gid) {
    union { float f; unsigned u; } v; v.f = sc;
    unsigned enc = (v.u & 0x80000000u) ? ~v.u : (v.u | 0x80000000u);  // monotone f32->u32
    return ((unsigned long long)enc << 32) | (unsigned)gid;
}

// ---------------- Stage 0: zero the top-k slots (ws is poisoned each launch) ----------------
__global__ void zero_slots_kernel(unsigned long long* __restrict__ slots) {
    int i = blockIdx.x * 256 + threadIdx.x;
    if (i < QQ * KTOP) slots[i] = 0ull;
}

// ---------------- Stage 1: f32 VALU scores + per-(q,chunk) top-10 -> atomic cascade -------
__launch_bounds__(256, 2)
__global__ void score_kernel(const int* __restrict__ rel, const int* __restrict__ head,
                             const float* __restrict__ E, const float* __restrict__ R,
                             unsigned long long* __restrict__ slots) {
    __shared__ __align__(16) float qv[QG * DD];   // 32 KB

    const int tid   = threadIdx.x;
    const int qg    = blockIdx.x >> 4;   // 0..31 query group
    const int chunk = blockIdx.x & 15;   // 0..15 n-chunk

    // ---- build the block's 32 qvecs in LDS: qv[q][d] = E[s1,head,d] * R[rel,d] (exact f32)
    {
        const int ql = tid >> 3, seg = tid & 7;
        const int qglob = qg * QG + ql;
        const int s1 = qglob >> 8;
        const float* eh = E + ((size_t)(s1 * PP + head[qglob])) * DD + seg * 32;
        const float* rr = R + (size_t)rel[qglob] * DD + seg * 32;
        #pragma unroll
        for (int c = 0; c < 8; c++) {
            f32x4 a = *(const f32x4*)(eh + c * 4);
            f32x4 b = *(const f32x4*)(rr + c * 4);
            *(f32x4*)(&qv[ql * DD + seg * 32 + c * 4]) = a * b;
        }
    }
    __syncthreads();

    // ---- main loop: thread = (q-quad qq, row-slot rs); 4 q x 4 rows register tile
    const int qq = tid >> 5;    // 0..7  -> queries qq*4 .. qq*4+3
    const int rs = tid & 31;    // 0..31 -> rows rs*4 .. rs*4+3 (+128 per iter)
    const int n0 = chunk * CHROWS;

    float ls[4][KTOP]; int lg[4][KTOP];   // ascending lists: ls[i][0] = min kept
    #pragma unroll
    for (int i = 0; i < 4; i++)
        #pragma unroll
        for (int k = 0; k < KTOP; k++) { ls[i][k] = -1e30f; lg[i][k] = 0; }

    const float* qb = &qv[(qq * 4) * DD];

    for (int it = 0; it < CHROWS / 128; it++) {
        const int nb = n0 + it * 128 + rs * 4;
        const float* r0 = E + (size_t)nb * DD;

        f32x4 acc[4][4];   // [qi][rowj], component-parallel partial sums
        #pragma unroll
        for (int i = 0; i < 4; i++)
            #pragma unroll
            for (int j = 0; j < 4; j++) acc[i][j] = (f32x4){0.f, 0.f, 0.f, 0.f};

        #pragma unroll 8
        for (int d4 = 0; d4 < DD / 4; d4++) {
            f32x4 er[4];
            #pragma unroll
            for (int j = 0; j < 4; j++) er[j] = *(const f32x4*)(r0 + j * DD + d4 * 4);
            #pragma unroll
            for (int i = 0; i < 4; i++) {
                f32x4 qvv = *(const f32x4*)(qb + i * DD + d4 * 4);
                #pragma unroll
                for (int j = 0; j < 4; j++) acc[i][j] += qvv * er[j];
            }
        }

        #pragma unroll
        for (int i = 0; i < 4; i++) {
            #pragma unroll
            for (int j = 0; j < 4; j++) {
                f32x4 a = acc[i][j];
                float s = (a[0] + a[1]) + (a[2] + a[3]);
                if (s > ls[i][0]) {
                    const int n = nb + j;
                    const int gid = ((n & (PP - 1)) << 2) | (n >> 15);   // p*4 + s2
                    #pragma unroll
                    for (int k = 0; k < KTOP - 1; k++) {
                        float nv = (ls[i][k + 1] < s) ? ls[i][k + 1] : ((ls[i][k] < s) ? s : ls[i][k]);
                        int   ni = (ls[i][k + 1] < s) ? lg[i][k + 1] : ((ls[i][k] < s) ? gid : lg[i][k]);
                        ls[i][k] = nv; lg[i][k] = ni;
                    }
                    if (ls[i][KTOP - 1] < s) { ls[i][KTOP - 1] = s; lg[i][KTOP - 1] = gid; }
                }
            }
        }
    }

    // ---- half-wave merge: the 32 lanes sharing qq hold 32 lists per q; selection-sort
    //      via butterfly argmax-pop, lane hl==0 feeds the atomicMax slot cascade.
    const int lane = tid & 63;
    const int hl   = lane & 31;
    #pragma unroll
    for (int i = 0; i < 4; i++) {
        const int qglob = qg * QG + qq * 4 + i;
        unsigned long long* s8 = slots + (size_t)qglob * KTOP;
        for (int r = 0; r < KTOP; r++) {
            float ps = ls[i][KTOP - 1]; int pg = lg[i][KTOP - 1]; int pl = hl;
            #pragma unroll
            for (int off = 16; off >= 1; off >>= 1) {
                float os = __shfl_xor(ps, off);
                int   og = __shfl_xor(pg, off);
                int   ol = __shfl_xor(pl, off);
                if (os > ps || (os == ps && ol < pl)) { ps = os; pg = og; pl = ol; }
            }
            if (hl == 0) {
                // exact concurrent top-10: slots are pointwise monotone under atomicMax;
                // carrying the displaced min preserves the global top-10 multiset.
                unsigned long long v = pack_sg(ps, pg);
                #pragma unroll
                for (int j = 0; j < KTOP; j++) {
                    unsigned long long old = atomicMax(&s8[j], v);
                    if (old < v) v = old;
                    if (v == 0ull) break;
                }
            }
            if (hl == pl) {   // owner pops its max
                #pragma unroll
                for (int k = KTOP - 1; k > 0; k--) { ls[i][k] = ls[i][k - 1]; lg[i][k] = lg[i][k - 1]; }
                ls[i][0] = -1e30f; lg[i][0] = 0;
            }
        }
    }
}

// ---------------- Stage 2: sort each q's 10 slots, write f32 gid + f32 score --------------
__global__ void finalize_kernel(const unsigned long long* __restrict__ slots,
                                float* __restrict__ out) {
    int q = blockIdx.x * 256 + threadIdx.x;
    if (q >= QQ) return;
    unsigned long long v[KTOP];
    #pragma unroll
    for (int i = 0; i < KTOP; i++) v[i] = slots[(size_t)q * KTOP + i];
    #pragma unroll
    for (int i = 1; i < KTOP; i++) {   // insertion sort descending
        unsigned long long key = v[i];
        int j = i - 1;
        while (j >= 0 && v[j] < key) { v[j + 1] = v[j]; j--; }
        v[j + 1] = key;
    }
    #pragma unroll
    for (int i = 0; i < KTOP; i++) {
        unsigned enc = (unsigned)(v[i] >> 32);
        union { unsigned u; float f; } w;
        w.u = (enc & 0x80000000u) ? (enc ^ 0x80000000u) : ~enc;
        unsigned gid = (unsigned)(v[i] & 0xFFFFFFFFu);
        out[q * KTOP + i]             = (float)gid;   // Output 0: gid (int-valued f32)
        out[QQ * KTOP + q * KTOP + i] = w.f;          // Output 1: score
    }
}

extern "C" void kernel_launch(void* const* d_in, const int* in_sizes, int n_in,
                              void* d_out, int out_size, void* d_ws, size_t ws_size,
                              hipStream_t stream) {
    const int*   rel  = (const int*)d_in[0];
    const int*   head = (const int*)d_in[1];
    const float* E    = (const float*)d_in[2];   // f32 per reference dtype
    const float* R    = (const float*)d_in[3];   // f32 per reference dtype

    unsigned long long* slots = (unsigned long long*)d_ws;   // 80 KiB

    zero_slots_kernel<<<dim3((QQ * KTOP + 255) / 256), dim3(256), 0, stream>>>(slots);
    score_kernel<<<dim3(QG ? (QQ / QG) * NCHUNK : 0), dim3(256), 0, stream>>>(rel, head, E, R, slots);
    finalize_kernel<<<dim3((QQ + 255) / 256), dim3(256), 0, stream>>>(slots, (float*)d_out);
}

// Round 6
// 1155.250 us; speedup vs baseline: 3.4507x; 3.4507x over previous
//
#include <hip/hip_runtime.h>

// Dtypes (established round 5): inputs int32/f32, outputs f32 (gid, score).
#define SS 4
#define BB 256
#define PP 32768
#define DD 256
#define QQ 1024          // SS*BB
#define NN 131072        // SS*PP candidate rows
#define KTOP 10
#define QTILE 128        // queries per block (8 waves x 16 q)
#define NCHUNK 64        // n-chunks
#define CHROWS 2048      // rows per chunk
#define PANEL 64         // rows per LDS panel
#define NPANEL (CHROWS / PANEL)   // 32
#define LSLOT 12         // per-lane candidate list
#define MSLOT 24         // global slots per query (approx top-24)
#define ROWG 33          // padded LDS row stride in 16B granules (64 rows)

typedef __attribute__((ext_vector_type(8))) short bf16x8;
typedef __attribute__((ext_vector_type(4))) float f32x4;

static __device__ __forceinline__ short f2bf(float f) {   // RNE
    union { float f; unsigned u; } v; v.f = f;
    unsigned r = (v.u + 0x7FFFu + ((v.u >> 16) & 1u)) >> 16;
    return (short)r;
}
static __device__ __forceinline__ bf16x8 cvt8(f32x4 a, f32x4 b) {
    bf16x8 r;
    r[0] = f2bf(a[0]); r[1] = f2bf(a[1]); r[2] = f2bf(a[2]); r[3] = f2bf(a[3]);
    r[4] = f2bf(b[0]); r[5] = f2bf(b[1]); r[6] = f2bf(b[2]); r[7] = f2bf(b[3]);
    return r;
}
static __device__ __forceinline__ unsigned long long pack_sg(float sc, int gid) {
    union { float f; unsigned u; } v; v.f = sc;
    unsigned enc = (v.u & 0x80000000u) ? ~v.u : (v.u | 0x80000000u);  // monotone f32->u32
    return ((unsigned long long)enc << 32) | (unsigned)gid;
}

// ---------------- Stage 0: zero the 24 slots per q (ws poisoned each launch) --------------
__global__ void zero_slots_kernel(unsigned long long* __restrict__ slots) {
    int i = blockIdx.x * 256 + threadIdx.x;
    if (i < QQ * MSLOT) slots[i] = 0ull;
}

// ---------------- Stage 1: bf16 MFMA approx scores -> per-q top-24 via atomic cascade -----
__launch_bounds__(512, 4)
__global__ void score_topk_kernel(const int* __restrict__ rel, const int* __restrict__ head,
                                  const float* __restrict__ E, const float* __restrict__ R,
                                  unsigned long long* __restrict__ slots) {
    // smem union:
    //   phase 0: A staging 128 q x 256 bf16                    = 65536 B
    //   main:    B panel 64 rows x 33 granules x 16 B = 33792  +
    //            scan 8 waves x (16 q x 68 f32) = 34816        = 68608 B
    //   merge:   8 waves x 768 u64-packed entries              = 49152 B
    __shared__ __align__(16) char smem[68608];

    const int tid  = threadIdx.x;
    const int wave = tid >> 6;
    const int lane = tid & 63;
    const int quad = lane >> 4;
    const int mrow = lane & 15;
    const int mtile = blockIdx.x >> 6;   // 0..7
    const int chunk = blockIdx.x & 63;   // 0..63

    // ---- Phase 0: qvec = E[s1,head]*R[rel], RNE->bf16, staged in LDS, frags to regs ----
    bf16x8 afrag[8];
    {
        short* ast = (short*)smem;
        const int qloc = tid >> 2, seg = tid & 3;       // 128 q x 4 segs of 64 d
        const int qglob = mtile * QTILE + qloc;
        const int s1 = qglob >> 8;
        const float* eh = E + ((size_t)(s1 * PP + head[qglob])) * DD + seg * 64;
        const float* rr = R + (size_t)rel[qglob] * DD + seg * 64;
        #pragma unroll
        for (int c8 = 0; c8 < 8; c8++) {
            f32x4 a0 = *(const f32x4*)(eh + c8 * 8);
            f32x4 a1 = *(const f32x4*)(eh + c8 * 8 + 4);
            f32x4 b0 = *(const f32x4*)(rr + c8 * 8);
            f32x4 b1 = *(const f32x4*)(rr + c8 * 8 + 4);
            *(bf16x8*)(ast + qloc * DD + seg * 64 + c8 * 8) = cvt8(a0 * b0, a1 * b1);
        }
        __syncthreads();
        const int arow = wave * 16 + mrow;   // A[m=lane&15][k=quad*8+j], k-base ks*32
        #pragma unroll
        for (int ks = 0; ks < 8; ks++)
            afrag[ks] = *(const bf16x8*)(ast + arow * DD + ks * 32 + quad * 8);
        __syncthreads();
    }

    short* bpan = (short*)smem;                                    // padded: row stride 264 bf16
    float* scan = (float*)(smem + 33792) + wave * (16 * 68);
    const int qi = lane >> 2;   // 0..15: q owned for scanning
    const int sl = lane & 3;    // 0..3 : 16-col slice
    const int n0c = chunk * CHROWS;

    float ls[LSLOT]; int lg[LSLOT];     // ascending: ls[0] = min kept
    #pragma unroll
    for (int i = 0; i < LSLOT; i++) { ls[i] = -1e30f; lg[i] = 0; }

    for (int panel = 0; panel < NPANEL; panel++) {
        const int n0 = n0c + panel * PANEL;
        __syncthreads();
        // stage: 2048 granules (64 rows x 32), f32 load -> bf16 -> padded LDS
        #pragma unroll
        for (int it = 0; it < 4; it++) {
            int gi = it * 512 + tid;
            int row = gi >> 5, slot = gi & 31;
            const float* src = E + (size_t)(n0 + row) * DD + slot * 8;
            f32x4 x0 = *(const f32x4*)(src);
            f32x4 x1 = *(const f32x4*)(src + 4);
            *(bf16x8*)(bpan + row * (ROWG * 8) + slot * 8) = cvt8(x0, x1);
        }
        __syncthreads();

        f32x4 acc[4];
        #pragma unroll
        for (int nt = 0; nt < 4; nt++) acc[nt] = (f32x4){0.f, 0.f, 0.f, 0.f};
        #pragma unroll
        for (int ks = 0; ks < 8; ks++) {
            #pragma unroll
            for (int nt = 0; nt < 4; nt++) {
                int brow = nt * 16 + mrow;   // B[n=lane&15][k=quad*8+j]
                bf16x8 b = *(const bf16x8*)(bpan + brow * (ROWG * 8) + ks * 32 + quad * 8);
                acc[nt] = __builtin_amdgcn_mfma_f32_16x16x32_bf16(afrag[ks], b, acc[nt], 0, 0, 0);
            }
        }
        // transpose via LDS: D[m=quad*4+reg][n=nt*16+mrow] -> lane (qi, sl) scans 16 cols
        #pragma unroll
        for (int nt = 0; nt < 4; nt++) {
            #pragma unroll
            for (int r = 0; r < 4; r++)
                scan[(quad * 4 + r) * 68 + nt * 16 + mrow] = acc[nt][r];
        }
        #pragma unroll
        for (int v4 = 0; v4 < 4; v4++) {
            f32x4 sv = *(const f32x4*)(scan + qi * 68 + sl * 16 + v4 * 4);
            #pragma unroll
            for (int e = 0; e < 4; e++) {
                float sc = sv[e];
                if (sc > ls[0]) {
                    int n = n0 + sl * 16 + v4 * 4 + e;
                    int gid = ((n & (PP - 1)) << 2) | (n >> 15);   // p*4 + s2
                    #pragma unroll
                    for (int i = 0; i < LSLOT - 1; i++) {
                        float nv = (ls[i + 1] < sc) ? ls[i + 1] : ((ls[i] < sc) ? sc : ls[i]);
                        int   ni = (ls[i + 1] < sc) ? lg[i + 1] : ((ls[i] < sc) ? gid : lg[i]);
                        ls[i] = nv; lg[i] = ni;
                    }
                    if (ls[LSLOT - 1] < sc) { ls[LSLOT - 1] = sc; lg[LSLOT - 1] = gid; }
                }
            }
        }
    }

    // ---- merge 4 slice-lists per q (packed u64 domain), push top-12 into global slots ----
    __syncthreads();
    unsigned long long* mw = (unsigned long long*)smem + (size_t)wave * 768;
    unsigned long long pl[LSLOT];
    #pragma unroll
    for (int i = 0; i < LSLOT; i++) pl[i] = pack_sg(ls[i], lg[i]);   // ascending
    #pragma unroll
    for (int i = 0; i < LSLOT; i++) mw[(qi * 4 + sl) * LSLOT + i] = pl[i];
    __syncthreads();
    if (sl == 0) {
        for (int o = 1; o < 4; o++) {
            #pragma unroll
            for (int j = 0; j < LSLOT; j++) {
                unsigned long long v = mw[(qi * 4 + o) * LSLOT + j];
                if (v > pl[0]) {
                    #pragma unroll
                    for (int i = 0; i < LSLOT - 1; i++)
                        pl[i] = (pl[i + 1] < v) ? pl[i + 1] : ((pl[i] < v) ? v : pl[i]);
                    if (pl[LSLOT - 1] < v) pl[LSLOT - 1] = v;
                }
            }
        }
        const int qglob = mtile * QTILE + wave * 16 + qi;
        unsigned long long* s8 = slots + (size_t)qglob * MSLOT;
        unsigned long long smin = s8[0];
        #pragma unroll
        for (int j = 1; j < MSLOT; j++) { unsigned long long t = s8[j]; if (t < smin) smin = t; }
        for (int i = LSLOT - 1; i >= 0; i--) {          // descending pushes
            unsigned long long v = pl[i];
            if (v <= smin) break;                       // stale-min filter (slots monotone)
            #pragma unroll
            for (int j = 0; j < MSLOT; j++) {
                unsigned long long old = atomicMax(&s8[j], v);
                if (old < v) v = old;                   // carry displaced value
                if (v == 0ull) break;
            }
        }
    }
}

// ---------------- Stage 2: exact f32 rescore of 24 candidates, top-10, write f32 ----------
__global__ void rescore_kernel(const int* __restrict__ rel, const int* __restrict__ head,
                               const float* __restrict__ E, const float* __restrict__ R,
                               const unsigned long long* __restrict__ slots,
                               float* __restrict__ out) {
    __shared__ float qv[DD];
    __shared__ float rsc[MSLOT];
    __shared__ int   rgid[MSLOT];

    const int q = blockIdx.x;
    const int tid = threadIdx.x;
    const int wave = tid >> 6, lane = tid & 63;
    const int s1 = q >> 8;

    qv[tid] = E[((size_t)(s1 * PP + head[q])) * DD + tid] * R[(size_t)rel[q] * DD + tid];
    __syncthreads();

    f32x4 qq = *(const f32x4*)(qv + lane * 4);
    #pragma unroll
    for (int c = 0; c < MSLOT / 4; c++) {
        int j = wave * (MSLOT / 4) + c;
        unsigned long long v = slots[(size_t)q * MSLOT + j];
        int gid = (int)(v & 0xFFFFFFFFu);
        int n = (gid & 3) * PP + (gid >> 2);
        f32x4 ev = *(const f32x4*)(E + (size_t)n * DD + lane * 4);
        f32x4 p = qq * ev;
        float s = (p[0] + p[1]) + (p[2] + p[3]);
        #pragma unroll
        for (int off = 32; off >= 1; off >>= 1) s += __shfl_xor(s, off);
        if (lane == 0) { rsc[j] = (v == 0ull) ? -1e30f : s; rgid[j] = gid; }
    }
    __syncthreads();

    if (tid < 64) {   // wave 0: argmax-pop 10 rounds over 24 entries
        float a = (tid < MSLOT) ? rsc[tid] : -1e30f;
        int   g = (tid < MSLOT) ? rgid[tid] : 0;
        for (int r = 0; r < KTOP; r++) {
            float ps = a; int pg = g; int plm = tid;
            #pragma unroll
            for (int off = 32; off >= 1; off >>= 1) {
                float os = __shfl_xor(ps, off);
                int   og = __shfl_xor(pg, off);
                int   ol = __shfl_xor(plm, off);
                if (os > ps || (os == ps && ol < plm)) { ps = os; pg = og; plm = ol; }
            }
            if (tid == 0) {
                out[q * KTOP + r]             = (float)pg;   // Output 0: gid
                out[QQ * KTOP + q * KTOP + r] = ps;          // Output 1: score
            }
            if (tid == plm) a = -1e30f;
        }
    }
}

extern "C" void kernel_launch(void* const* d_in, const int* in_sizes, int n_in,
                              void* d_out, int out_size, void* d_ws, size_t ws_size,
                              hipStream_t stream) {
    const int*   rel  = (const int*)d_in[0];
    const int*   head = (const int*)d_in[1];
    const float* E    = (const float*)d_in[2];
    const float* R    = (const float*)d_in[3];

    unsigned long long* slots = (unsigned long long*)d_ws;   // QQ*24*8 = 192 KiB

    zero_slots_kernel<<<dim3((QQ * MSLOT + 255) / 256), dim3(256), 0, stream>>>(slots);
    score_topk_kernel<<<dim3((QQ / QTILE) * NCHUNK), dim3(512), 0, stream>>>(rel, head, E, R, slots);
    rescore_kernel<<<dim3(QQ), dim3(256), 0, stream>>>(rel, head, E, R, slots, (float*)d_out);
}

// Round 7
// 482.140 us; speedup vs baseline: 8.2682x; 2.3961x over previous
//
#include <hip/hip_runtime.h>

// Dtypes (established round 5): inputs int32/f32, outputs f32 (gid, score).
#define SS 4
#define BB 256
#define PP 32768
#define DD 256
#define QQ 1024          // SS*BB
#define NN 131072        // SS*PP candidate rows
#define KTOP 10
#define QTILE 128        // queries per block (8 waves x 16 q)
#define NCHUNK 64        // n-chunks
#define CHROWS 2048      // rows per chunk
#define PANEL 64         // rows per LDS panel
#define NPANEL (CHROWS / PANEL)   // 32
#define LSLOT 8          // per-lane candidate list
#define JCH 8            // per-(q,chunk) emitted list
#define MSLOT 20         // global approx top per q (rescored exactly)
#define ROWG 33          // padded LDS row stride in 16B granules
#define ROWE (ROWG * 8)  // row stride in bf16 units (264)
#define PANB (PANEL * ROWG * 16)  // 33792 B per panel buffer

typedef __attribute__((ext_vector_type(8))) short bf16x8;
typedef __attribute__((ext_vector_type(4))) float f32x4;

static __device__ __forceinline__ short f2bf(float f) {   // RNE
    union { float f; unsigned u; } v; v.f = f;
    unsigned r = (v.u + 0x7FFFu + ((v.u >> 16) & 1u)) >> 16;
    return (short)r;
}
static __device__ __forceinline__ bf16x8 cvt8(f32x4 a, f32x4 b) {
    bf16x8 r;
    r[0] = f2bf(a[0]); r[1] = f2bf(a[1]); r[2] = f2bf(a[2]); r[3] = f2bf(a[3]);
    r[4] = f2bf(b[0]); r[5] = f2bf(b[1]); r[6] = f2bf(b[2]); r[7] = f2bf(b[3]);
    return r;
}
static __device__ __forceinline__ unsigned long long pack_sg(float sc, int gid) {
    union { float f; unsigned u; } v; v.f = sc;
    unsigned enc = (v.u & 0x80000000u) ? ~v.u : (v.u | 0x80000000u);  // monotone f32->u32
    return ((unsigned long long)enc << 32) | (unsigned)gid;
}

// ---------------- Stage 0a: E f32 -> bf16 (once; removes all in-loop cvt VALU) ------------
__global__ void convert_e_kernel(const float* __restrict__ E, short* __restrict__ Ebf) {
    size_t i = ((size_t)blockIdx.x * 256 + threadIdx.x) * 8;
    f32x4 a = *(const f32x4*)(E + i);
    f32x4 b = *(const f32x4*)(E + i + 4);
    *(bf16x8*)(Ebf + i) = cvt8(a, b);
}

// ---------------- Stage 0b: qvec = E[s1,head]*R[rel] (f32 exact) -> bf16 ------------------
__global__ void qvec_kernel(const int* __restrict__ rel, const int* __restrict__ head,
                            const float* __restrict__ E, const float* __restrict__ R,
                            short* __restrict__ qbf) {
    int q = blockIdx.x, d = threadIdx.x;
    int s1 = q >> 8;
    float f = E[((size_t)(s1 * PP + head[q])) * DD + d] * R[(size_t)rel[q] * DD + d];
    qbf[q * DD + d] = f2bf(f);
}

// ---------------- Stage 1: bf16 MFMA, double-buffered panels, per-(q,chunk) top-8 ---------
__launch_bounds__(512, 4)
__global__ void score_topk_kernel(const short* __restrict__ Ebf, const short* __restrict__ qbf,
                                  unsigned long long* __restrict__ parts) {
    // LDS: 2 x panel (64 rows x 33 granules x 16B = 33792) + 8 waves x (16q x 20 f32)
    __shared__ __align__(16) char smem[2 * PANB + 8 * 1280];

    const int tid  = threadIdx.x;
    const int wave = tid >> 6;
    const int lane = tid & 63;
    const int quad = lane >> 4;
    const int mrow = lane & 15;
    const int mtile = blockIdx.x >> 6;   // 0..7
    const int chunk = blockIdx.x & 63;   // 0..63

    short* buf0 = (short*)smem;
    short* buf1 = (short*)(smem + PANB);
    float* scan = (float*)(smem + 2 * PANB) + wave * 320;   // 16 x 20 f32

    // A fragments straight from pre-built bf16 qvec: A[m=lane&15][k=quad*8+j]
    bf16x8 afrag[8];
    {
        const int arow = mtile * QTILE + wave * 16 + mrow;
        #pragma unroll
        for (int ks = 0; ks < 8; ks++)
            afrag[ks] = *(const bf16x8*)(qbf + arow * DD + ks * 32 + quad * 8);
    }

    float ls[LSLOT]; int lg[LSLOT];   // ascending: ls[0] = min kept
    #pragma unroll
    for (int i = 0; i < LSLOT; i++) { ls[i] = -1e30f; lg[i] = 0; }

    const int qi = lane >> 2;   // 0..15
    const int sl = lane & 3;    // 0..3
    const int n0c = chunk * CHROWS;

    // prologue: stage panel 0 into buf0
    bf16x8 st[4];
    #pragma unroll
    for (int it = 0; it < 4; it++) {
        int gi = it * 512 + tid, row = gi >> 5, slot = gi & 31;
        st[it] = *(const bf16x8*)(Ebf + (size_t)(n0c + row) * DD + slot * 8);
    }
    #pragma unroll
    for (int it = 0; it < 4; it++) {
        int gi = it * 512 + tid, row = gi >> 5, slot = gi & 31;
        *(bf16x8*)(buf0 + row * ROWE + slot * 8) = st[it];
    }

    for (int p = 0; p < NPANEL; p++) {
        short* bp = (p & 1) ? buf1 : buf0;
        short* bn = (p & 1) ? buf0 : buf1;
        const int n0 = n0c + p * PANEL;
        __syncthreads();   // current buffer's stores visible; prior readers of bn done
        if (p + 1 < NPANEL) {   // issue next panel's loads; they overlap the compute below
            const int n1 = n0 + PANEL;
            #pragma unroll
            for (int it = 0; it < 4; it++) {
                int gi = it * 512 + tid, row = gi >> 5, slot = gi & 31;
                st[it] = *(const bf16x8*)(Ebf + (size_t)(n1 + row) * DD + slot * 8);
            }
        }

        f32x4 acc[4];
        #pragma unroll
        for (int nt = 0; nt < 4; nt++) acc[nt] = (f32x4){0.f, 0.f, 0.f, 0.f};
        #pragma unroll
        for (int ks = 0; ks < 8; ks++) {
            #pragma unroll
            for (int nt = 0; nt < 4; nt++) {
                int brow = nt * 16 + mrow;   // B[n=lane&15][k=quad*8+j]
                bf16x8 b = *(const bf16x8*)(bp + brow * ROWE + ks * 32 + quad * 8);
                acc[nt] = __builtin_amdgcn_mfma_f32_16x16x32_bf16(afrag[ks], b, acc[nt], 0, 0, 0);
            }
        }

        // per-nt scan through a small per-wave LDS tile (same-wave in-order LDS)
        #pragma unroll
        for (int nt = 0; nt < 4; nt++) {
            #pragma unroll
            for (int r = 0; r < 4; r++)
                scan[(quad * 4 + r) * 20 + mrow] = acc[nt][r];   // D[m=quad*4+r][n=mrow]
            f32x4 sv = *(const f32x4*)(scan + qi * 20 + sl * 4);
            #pragma unroll
            for (int e = 0; e < 4; e++) {
                float sc = sv[e];
                if (sc > ls[0]) {
                    int n = n0 + nt * 16 + sl * 4 + e;
                    int gid = ((n & (PP - 1)) << 2) | (n >> 15);   // p*4 + s2
                    #pragma unroll
                    for (int i = 0; i < LSLOT - 1; i++) {
                        float nv = (ls[i + 1] < sc) ? ls[i + 1] : ((ls[i] < sc) ? sc : ls[i]);
                        int   ni = (ls[i + 1] < sc) ? lg[i + 1] : ((ls[i] < sc) ? gid : lg[i]);
                        ls[i] = nv; lg[i] = ni;
                    }
                    if (ls[LSLOT - 1] < sc) { ls[LSLOT - 1] = sc; lg[LSLOT - 1] = gid; }
                }
            }
        }

        if (p + 1 < NPANEL) {   // write prefetched panel into the other buffer
            #pragma unroll
            for (int it = 0; it < 4; it++) {
                int gi = it * 512 + tid, row = gi >> 5, slot = gi & 31;
                *(bf16x8*)(bn + row * ROWE + slot * 8) = st[it];
            }
        }
    }

    // ---- merge 4 slice-lists per q in packed u64 domain; plain stores (no atomics) ----
    __syncthreads();   // all waves done with buffers; reuse buf0 as per-wave staging
    unsigned long long* mw = (unsigned long long*)smem + (size_t)wave * 512;
    unsigned long long pl[LSLOT];
    #pragma unroll
    for (int i = 0; i < LSLOT; i++) pl[i] = pack_sg(ls[i], lg[i]);   // ascending
    #pragma unroll
    for (int i = 0; i < LSLOT; i++) mw[(qi * 4 + sl) * LSLOT + i] = pl[i];
    if (sl == 0) {   // same-wave LDS ordering: writes above visible to this wave's reads
        for (int o = 1; o < 4; o++) {
            #pragma unroll
            for (int j = 0; j < LSLOT; j++) {
                unsigned long long v = mw[(qi * 4 + o) * LSLOT + j];
                if (v > pl[0]) {
                    #pragma unroll
                    for (int i = 0; i < LSLOT - 1; i++)
                        pl[i] = (pl[i + 1] < v) ? pl[i + 1] : ((pl[i] < v) ? v : pl[i]);
                    if (pl[LSLOT - 1] < v) pl[LSLOT - 1] = v;
                }
            }
        }
        const int qg = mtile * QTILE + wave * 16 + qi;
        unsigned long long* dst = parts + ((size_t)qg * NCHUNK + chunk) * JCH;
        #pragma unroll
        for (int i = 0; i < JCH; i++) dst[i] = pl[LSLOT - 1 - i];   // descending run
    }
}

// ---------------- Stage 2: merge 64 runs of 8 per q -> approx top-20 ----------------------
__global__ void merge_kernel(const unsigned long long* __restrict__ parts,
                             unsigned long long* __restrict__ top20) {
    const int wave = threadIdx.x >> 6;
    const int lane = threadIdx.x & 63;   // lane = chunk
    const int q = blockIdx.x * 4 + wave;

    unsigned long long run[JCH];   // descending
    const unsigned long long* src = parts + ((size_t)q * NCHUNK + lane) * JCH;
    #pragma unroll
    for (int j = 0; j < JCH; j++) run[j] = src[j];

    for (int r = 0; r < MSLOT; r++) {
        unsigned long long best = run[0]; int bl = lane;
        #pragma unroll
        for (int off = 32; off >= 1; off >>= 1) {
            unsigned long long ob = __shfl_xor(best, off);
            int ol = __shfl_xor(bl, off);
            if (ob > best) { best = ob; bl = ol; }
        }
        if (lane == 0) top20[(size_t)q * MSLOT + r] = best;
        if (lane == bl) {   // winner pops its head
            #pragma unroll
            for (int j = 0; j < JCH - 1; j++) run[j] = run[j + 1];
            run[JCH - 1] = 0ull;
        }
    }
}

// ---------------- Stage 3: exact f32 rescore of 20 candidates, top-10, write f32 ----------
__global__ void rescore_kernel(const int* __restrict__ rel, const int* __restrict__ head,
                               const float* __restrict__ E, const float* __restrict__ R,
                               const unsigned long long* __restrict__ top20,
                               float* __restrict__ out) {
    __shared__ float qv[DD];
    __shared__ float rsc[MSLOT];
    __shared__ int   rgid[MSLOT];

    const int q = blockIdx.x;
    const int tid = threadIdx.x;
    const int wave = tid >> 6, lane = tid & 63;
    const int s1 = q >> 8;

    qv[tid] = E[((size_t)(s1 * PP + head[q])) * DD + tid] * R[(size_t)rel[q] * DD + tid];
    __syncthreads();

    f32x4 qq = *(const f32x4*)(qv + lane * 4);
    #pragma unroll
    for (int c = 0; c < MSLOT / 4; c++) {   // 5 candidates per wave
        int j = wave * (MSLOT / 4) + c;
        unsigned long long v = top20[(size_t)q * MSLOT + j];
        int gid = (int)(v & 0xFFFFFFFFu);
        int n = (gid & 3) * PP + (gid >> 2);
        f32x4 ev = *(const f32x4*)(E + (size_t)n * DD + lane * 4);
        f32x4 p = qq * ev;
        float s = (p[0] + p[1]) + (p[2] + p[3]);
        #pragma unroll
        for (int off = 32; off >= 1; off >>= 1) s += __shfl_xor(s, off);
        if (lane == 0) { rsc[j] = (v == 0ull) ? -1e30f : s; rgid[j] = gid; }
    }
    __syncthreads();

    if (tid < 64) {   // wave 0: argmax-pop 10 rounds over 20 entries
        float a = (tid < MSLOT) ? rsc[tid] : -1e30f;
        int   g = (tid < MSLOT) ? rgid[tid] : 0;
        for (int r = 0; r < KTOP; r++) {
            float ps = a; int pg = g; int plm = tid;
            #pragma unroll
            for (int off = 32; off >= 1; off >>= 1) {
                float os = __shfl_xor(ps, off);
                int   og = __shfl_xor(pg, off);
                int   ol = __shfl_xor(plm, off);
                if (os > ps || (os == ps && ol < plm)) { ps = os; pg = og; plm = ol; }
            }
            if (tid == 0) {
                out[q * KTOP + r]             = (float)pg;   // Output 0: gid
                out[QQ * KTOP + q * KTOP + r] = ps;          // Output 1: score
            }
            if (tid == plm) a = -1e30f;
        }
    }
}

extern "C" void kernel_launch(void* const* d_in, const int* in_sizes, int n_in,
                              void* d_out, int out_size, void* d_ws, size_t ws_size,
                              hipStream_t stream) {
    const int*   rel  = (const int*)d_in[0];
    const int*   head = (const int*)d_in[1];
    const float* E    = (const float*)d_in[2];
    const float* R    = (const float*)d_in[3];

    char* ws = (char*)d_ws;
    short* Ebf  = (short*)ws;                                        // 67,108,864 B
    short* qbf  = (short*)(ws + (size_t)NN * DD * 2);                //    524,288 B
    unsigned long long* parts = (unsigned long long*)(ws + (size_t)NN * DD * 2 + (size_t)QQ * DD * 2);          // 4,194,304 B
    unsigned long long* top20 = (unsigned long long*)((char*)parts + (size_t)QQ * NCHUNK * JCH * 8);            //   163,840 B

    convert_e_kernel<<<dim3(NN * DD / 8 / 256), dim3(256), 0, stream>>>(E, Ebf);
    qvec_kernel<<<dim3(QQ), dim3(DD), 0, stream>>>(rel, head, E, R, qbf);
    score_topk_kernel<<<dim3((QQ / QTILE) * NCHUNK), dim3(512), 0, stream>>>(Ebf, qbf, parts);
    merge_kernel<<<dim3(QQ / 4), dim3(256), 0, stream>>>(parts, top20);
    rescore_kernel<<<dim3(QQ), dim3(256), 0, stream>>>(rel, head, E, R, top20, (float*)d_out);
}

// Round 8
// 320.751 us; speedup vs baseline: 12.4284x; 1.5032x over previous
//
#include <hip/hip_runtime.h>

// Dtypes (established round 5): inputs int32/f32, outputs f32 (gid, score).
#define SS 4
#define BB 256
#define PP 32768
#define DD 256
#define QQ 1024          // SS*BB
#define NN 131072        // SS*PP candidate rows
#define KTOP 10
#define QTILE 128        // queries per block (8 waves x 16 q)
#define NCHUNK 64        // n-chunks
#define CHROWS 2048      // rows per chunk
#define PANEL 64         // rows per LDS panel
#define NPANEL (CHROWS / PANEL)   // 32
#define JCH 8            // per-(q,chunk) survivors (sorted desc run)
#define MSLOT 20         // global approx survivors per q (exact-rescored)
#define ROWG 33          // padded LDS row stride in 16B granules
#define ROWE (ROWG * 8)  // row stride in bf16 units (264)
#define PANB (PANEL * ROWG * 16)  // 33792 B per panel buffer
#define KEYMASK 0xFFFFF800u       // keep 21 score bits, low 11 = column

typedef __attribute__((ext_vector_type(8))) short bf16x8;
typedef __attribute__((ext_vector_type(4))) float f32x4;
typedef __attribute__((ext_vector_type(4))) unsigned int u32x4;

static __device__ __forceinline__ short f2bf(float f) {   // RNE
    union { float f; unsigned u; } v; v.f = f;
    unsigned r = (v.u + 0x7FFFu + ((v.u >> 16) & 1u)) >> 16;
    return (short)r;
}
static __device__ __forceinline__ bf16x8 cvt8(f32x4 a, f32x4 b) {
    bf16x8 r;
    r[0] = f2bf(a[0]); r[1] = f2bf(a[1]); r[2] = f2bf(a[2]); r[3] = f2bf(a[3]);
    r[4] = f2bf(b[0]); r[5] = f2bf(b[1]); r[6] = f2bf(b[2]); r[7] = f2bf(b[3]);
    return r;
}
static __device__ __forceinline__ unsigned umax(unsigned a, unsigned b) { return a > b ? a : b; }
static __device__ __forceinline__ unsigned umin(unsigned a, unsigned b) { return a < b ? a : b; }

// ---------------- Stage 0a: E f32 -> bf16 (once) ------------------------------------------
__global__ void convert_e_kernel(const float* __restrict__ E, short* __restrict__ Ebf) {
    size_t i = ((size_t)blockIdx.x * 256 + threadIdx.x) * 8;
    f32x4 a = *(const f32x4*)(E + i);
    f32x4 b = *(const f32x4*)(E + i + 4);
    *(bf16x8*)(Ebf + i) = cvt8(a, b);
}

// ---------------- Stage 0b: qvec = E[s1,head]*R[rel] (f32 exact) -> bf16 ------------------
__global__ void qvec_kernel(const int* __restrict__ rel, const int* __restrict__ head,
                            const float* __restrict__ E, const float* __restrict__ R,
                            short* __restrict__ qbf) {
    int q = blockIdx.x, d = threadIdx.x;
    int s1 = q >> 8;
    float f = E[((size_t)(s1 * PP + head[q])) * DD + d] * R[(size_t)rel[q] * DD + d];
    qbf[q * DD + d] = f2bf(f);
}

// ---------------- Stage 1: bf16 MFMA + branchless packed-u32 top-k ------------------------
__launch_bounds__(512, 4)
__global__ void score_topk_kernel(const short* __restrict__ Ebf, const short* __restrict__ qbf,
                                  unsigned* __restrict__ parts) {
    // LDS: 2 x panel buffers (64 rows x 33 granules x 16B). End-merge reuses buf0.
    __shared__ __align__(16) char smem[2 * PANB];

    const int tid  = threadIdx.x;
    const int wave = tid >> 6;
    const int lane = tid & 63;
    const int quad = lane >> 4;
    const int mrow = lane & 15;
    const int mtile = blockIdx.x >> 6;   // 0..7
    const int chunk = blockIdx.x & 63;   // 0..63

    short* buf0 = (short*)smem;
    short* buf1 = (short*)(smem + PANB);

    // A fragments from pre-built bf16 qvec: A[m=lane&15][k=quad*8+j]
    bf16x8 afrag[8];
    {
        const int arow = mtile * QTILE + wave * 16 + mrow;
        #pragma unroll
        for (int ks = 0; ks < 8; ks++)
            afrag[ks] = *(const bf16x8*)(qbf + arow * DD + ks * 32 + quad * 8);
    }

    // per-lane per-q ascending 4-deep lists of packed keys (score-hi | col)
    unsigned lst[4][4];
    #pragma unroll
    for (int r = 0; r < 4; r++)
        #pragma unroll
        for (int i = 0; i < 4; i++) lst[r][i] = 0u;

    const int n0c = chunk * CHROWS;

    // prologue: stage panel 0 into buf0
    bf16x8 st[4];
    #pragma unroll
    for (int it = 0; it < 4; it++) {
        int gi = it * 512 + tid, row = gi >> 5, slot = gi & 31;
        st[it] = *(const bf16x8*)(Ebf + (size_t)(n0c + row) * DD + slot * 8);
    }
    #pragma unroll
    for (int it = 0; it < 4; it++) {
        int gi = it * 512 + tid, row = gi >> 5, slot = gi & 31;
        *(bf16x8*)(buf0 + row * ROWE + slot * 8) = st[it];
    }

    int pc = mrow;   // rolling column base: panel*64 + mrow

    for (int p = 0; p < NPANEL; p++) {
        short* bp = (p & 1) ? buf1 : buf0;
        short* bn = (p & 1) ? buf0 : buf1;
        __syncthreads();
        if (p + 1 < NPANEL) {   // prefetch next panel (overlaps compute)
            const int n1 = n0c + (p + 1) * PANEL;
            #pragma unroll
            for (int it = 0; it < 4; it++) {
                int gi = it * 512 + tid, row = gi >> 5, slot = gi & 31;
                st[it] = *(const bf16x8*)(Ebf + (size_t)(n1 + row) * DD + slot * 8);
            }
        }

        f32x4 acc[4];
        #pragma unroll
        for (int nt = 0; nt < 4; nt++) acc[nt] = (f32x4){0.f, 0.f, 0.f, 0.f};
        #pragma unroll
        for (int ks = 0; ks < 8; ks++) {
            #pragma unroll
            for (int nt = 0; nt < 4; nt++) {
                int brow = nt * 16 + mrow;   // B[n=lane&15][k=quad*8+j]
                bf16x8 b = *(const bf16x8*)(bp + brow * ROWE + ks * 32 + quad * 8);
                acc[nt] = __builtin_amdgcn_mfma_f32_16x16x32_bf16(afrag[ks], b, acc[nt], 0, 0, 0);
            }
        }

        // branchless scan straight from C-layout regs: lane owns q=quad*4+r, col=pc+nt*16
        #pragma unroll
        for (int nt = 0; nt < 4; nt++) {
            const unsigned coln = (unsigned)(pc + nt * 16);
            #pragma unroll
            for (int r = 0; r < 4; r++) {
                unsigned enc = __float_as_uint(acc[nt][r] + 256.0f);
                unsigned key = (enc & KEYMASK) | coln;
                unsigned n0 = umin(umax(key, lst[r][0]), lst[r][1]);
                unsigned n1 = umin(umax(key, lst[r][1]), lst[r][2]);
                unsigned n2 = umin(umax(key, lst[r][2]), lst[r][3]);
                unsigned n3 = umax(key, lst[r][3]);
                lst[r][0] = n0; lst[r][1] = n1; lst[r][2] = n2; lst[r][3] = n3;
            }
        }
        pc += 64;

        if (p + 1 < NPANEL) {
            #pragma unroll
            for (int it = 0; it < 4; it++) {
                int gi = it * 512 + tid, row = gi >> 5, slot = gi & 31;
                *(bf16x8*)(bn + row * ROWE + slot * 8) = st[it];
            }
        }
    }

    // ---- end of chunk: per-wave LDS dump; 16 lanes build per-(q,chunk) sorted top-8 ----
    // buf0 is free for all waves after the final barrier (last reads were p=30/p=31 region-safe)
    unsigned* mw = (unsigned*)(smem + wave * 4096);   // 16 q x 16 lanes x 4 keys
    #pragma unroll
    for (int r = 0; r < 4; r++) {
        u32x4 v; v[0] = lst[r][0]; v[1] = lst[r][1]; v[2] = lst[r][2]; v[3] = lst[r][3];
        *(u32x4*)(mw + (quad * 4 + r) * 64 + mrow * 4) = v;
    }
    if (lane < 16) {   // lane handles q_local = lane: top-8 of its 64 keys
        unsigned rr[JCH];
        #pragma unroll
        for (int i = 0; i < JCH; i++) rr[i] = 0u;
        #pragma unroll
        for (int j = 0; j < 16; j++) {
            u32x4 v = *(const u32x4*)(mw + lane * 64 + j * 4);
            #pragma unroll
            for (int e = 0; e < 4; e++) {
                unsigned x = v[e];
                unsigned t0 = umin(umax(x, rr[0]), rr[1]);
                unsigned t1 = umin(umax(x, rr[1]), rr[2]);
                unsigned t2 = umin(umax(x, rr[2]), rr[3]);
                unsigned t3 = umin(umax(x, rr[3]), rr[4]);
                unsigned t4 = umin(umax(x, rr[4]), rr[5]);
                unsigned t5 = umin(umax(x, rr[5]), rr[6]);
                unsigned t6 = umin(umax(x, rr[6]), rr[7]);
                unsigned t7 = umax(x, rr[7]);
                rr[0]=t0; rr[1]=t1; rr[2]=t2; rr[3]=t3; rr[4]=t4; rr[5]=t5; rr[6]=t6; rr[7]=t7;
            }
        }
        const int qg = mtile * QTILE + wave * 16 + lane;
        unsigned* dst = parts + ((size_t)qg * NCHUNK + chunk) * JCH;
        #pragma unroll
        for (int i = 0; i < JCH; i++) dst[i] = rr[JCH - 1 - i];   // descending run
    }
}

// ---------------- Stage 2: fused merge (lane=chunk, 20 pops) + exact f32 rescore ----------
__global__ void finalize_kernel(const int* __restrict__ rel, const int* __restrict__ head,
                                const float* __restrict__ E, const float* __restrict__ R,
                                const unsigned* __restrict__ parts, float* __restrict__ out) {
    __shared__ float qv[DD];
    __shared__ int   gl[MSLOT];
    __shared__ float rsc[MSLOT];
    __shared__ int   rgid[MSLOT];

    const int q = blockIdx.x;
    const int tid = threadIdx.x;
    const int wave = tid >> 6, lane = tid & 63;
    const int s1 = q >> 8;

    qv[tid] = E[((size_t)(s1 * PP + head[q])) * DD + tid] * R[(size_t)rel[q] * DD + tid];

    if (wave == 0) {   // lane = chunk; 20 argmax-pops over 64 sorted-desc runs of 8
        unsigned run[JCH];
        const unsigned* src = parts + ((size_t)q * NCHUNK + lane) * JCH;
        #pragma unroll
        for (int j = 0; j < JCH; j++) run[j] = src[j];
        for (int r = 0; r < MSLOT; r++) {
            unsigned best = run[0]; int bl = lane;
            #pragma unroll
            for (int off = 32; off >= 1; off >>= 1) {
                unsigned ob = __shfl_xor(best, off);
                int ol = __shfl_xor(bl, off);
                if (ob > best || (ob == best && ol < bl)) { best = ob; bl = ol; }
            }
            if (lane == bl) {
                int col = (int)(best & 0x7FFu);
                int n = lane * CHROWS + col;
                gl[r] = ((n & (PP - 1)) << 2) | (n >> 15);   // gid = p*4 + s2
                #pragma unroll
                for (int j = 0; j < JCH - 1; j++) run[j] = run[j + 1];
                run[JCH - 1] = 0u;
            }
        }
    }
    __syncthreads();

    // exact f32 rescore: wave w handles candidates w*5 .. w*5+4
    f32x4 qq = *(const f32x4*)(qv + lane * 4);
    #pragma unroll
    for (int c = 0; c < MSLOT / 4; c++) {
        int j = wave * (MSLOT / 4) + c;
        int gid = gl[j];
        int n = (gid & 3) * PP + (gid >> 2);
        f32x4 ev = *(const f32x4*)(E + (size_t)n * DD + lane * 4);
        f32x4 p = qq * ev;
        float s = (p[0] + p[1]) + (p[2] + p[3]);
        #pragma unroll
        for (int off = 32; off >= 1; off >>= 1) s += __shfl_xor(s, off);
        if (lane == 0) { rsc[j] = s; rgid[j] = gid; }
    }
    __syncthreads();

    if (tid < 64) {   // wave 0: 10 argmax-pops over 20 exact scores
        float a = (tid < MSLOT) ? rsc[tid] : -1e30f;
        int   g = (tid < MSLOT) ? rgid[tid] : 0;
        for (int r = 0; r < KTOP; r++) {
            float ps = a; int pg = g; int plm = tid;
            #pragma unroll
            for (int off = 32; off >= 1; off >>= 1) {
                float os = __shfl_xor(ps, off);
                int   og = __shfl_xor(pg, off);
                int   ol = __shfl_xor(plm, off);
                if (os > ps || (os == ps && ol < plm)) { ps = os; pg = og; plm = ol; }
            }
            if (tid == 0) {
                out[q * KTOP + r]             = (float)pg;   // Output 0: gid
                out[QQ * KTOP + q * KTOP + r] = ps;          // Output 1: score
            }
            if (tid == plm) a = -1e30f;
        }
    }
}

extern "C" void kernel_launch(void* const* d_in, const int* in_sizes, int n_in,
                              void* d_out, int out_size, void* d_ws, size_t ws_size,
                              hipStream_t stream) {
    const int*   rel  = (const int*)d_in[0];
    const int*   head = (const int*)d_in[1];
    const float* E    = (const float*)d_in[2];
    const float* R    = (const float*)d_in[3];

    char* ws = (char*)d_ws;
    short* Ebf = (short*)ws;                                   // 67,108,864 B
    short* qbf = (short*)(ws + (size_t)NN * DD * 2);           //    524,288 B
    unsigned* parts = (unsigned*)(ws + (size_t)NN * DD * 2 + (size_t)QQ * DD * 2);   // 2,097,152 B

    convert_e_kernel<<<dim3(NN * DD / 8 / 256), dim3(256), 0, stream>>>(E, Ebf);
    qvec_kernel<<<dim3(QQ), dim3(DD), 0, stream>>>(rel, head, E, R, qbf);
    score_topk_kernel<<<dim3((QQ / QTILE) * NCHUNK), dim3(512), 0, stream>>>(Ebf, qbf, parts);
    finalize_kernel<<<dim3(QQ), dim3(256), 0, stream>>>(rel, head, E, R, parts, (float*)d_out);
}

// Round 9
// 309.738 us; speedup vs baseline: 12.8704x; 1.0356x over previous
//
#include <hip/hip_runtime.h>

// Dtypes (established round 5): inputs int32/f32, outputs f32 (gid, score).
#define SS 4
#define BB 256
#define PP 32768
#define DD 256
#define QQ 1024          // SS*BB
#define NN 131072        // SS*PP candidate rows
#define KTOP 10
#define QTILE 128        // queries per block (4 waves x 32 q)
#define WQ 32            // q per wave (32x32 MFMA)
#define NCHUNK 64        // n-chunks
#define CHROWS 2048      // rows per chunk
#define PANEL 64         // rows per LDS panel
#define NPANEL (CHROWS / PANEL)   // 32
#define JCH 8            // per-(q,chunk) survivors (sorted desc run)
#define MSLOT 20         // global approx survivors per q (exact-rescored)
#define ROWG 33          // padded LDS row stride in 16B granules
#define ROWE (ROWG * 8)  // row stride in bf16 units (264)
#define PANB (PANEL * ROWG * 16)  // 33792 B per panel buffer
#define KEYMASK 0xFFFFF800u       // keep 21 score bits, low 11 = column
#define MWS 132          // merge-stage row stride in u32 (bank-spread, 16B-aligned)

typedef __attribute__((ext_vector_type(8))) short bf16x8;
typedef __attribute__((ext_vector_type(4))) float f32x4;
typedef __attribute__((ext_vector_type(16))) float f32x16;
typedef __attribute__((ext_vector_type(4))) unsigned int u32x4;

static __device__ __forceinline__ short f2bf(float f) {   // RNE
    union { float f; unsigned u; } v; v.f = f;
    unsigned r = (v.u + 0x7FFFu + ((v.u >> 16) & 1u)) >> 16;
    return (short)r;
}
static __device__ __forceinline__ bf16x8 cvt8(f32x4 a, f32x4 b) {
    bf16x8 r;
    r[0] = f2bf(a[0]); r[1] = f2bf(a[1]); r[2] = f2bf(a[2]); r[3] = f2bf(a[3]);
    r[4] = f2bf(b[0]); r[5] = f2bf(b[1]); r[6] = f2bf(b[2]); r[7] = f2bf(b[3]);
    return r;
}
static __device__ __forceinline__ unsigned umax(unsigned a, unsigned b) { return a > b ? a : b; }
static __device__ __forceinline__ unsigned umin(unsigned a, unsigned b) { return a < b ? a : b; }

// ---------------- Stage 0: E f32->bf16 AND qvec build, one launch ------------------------
__global__ void prep_kernel(const int* __restrict__ rel, const int* __restrict__ head,
                            const float* __restrict__ E, const float* __restrict__ R,
                            short* __restrict__ Ebf, short* __restrict__ qbf) {
    if (blockIdx.x < NN * DD / 8 / 256) {
        size_t i = ((size_t)blockIdx.x * 256 + threadIdx.x) * 8;
        f32x4 a = *(const f32x4*)(E + i);
        f32x4 b = *(const f32x4*)(E + i + 4);
        *(bf16x8*)(Ebf + i) = cvt8(a, b);
    } else {
        int q = blockIdx.x - NN * DD / 8 / 256, d = threadIdx.x;
        int s1 = q >> 8;
        float f = E[((size_t)(s1 * PP + head[q])) * DD + d] * R[(size_t)rel[q] * DD + d];
        qbf[q * DD + d] = f2bf(f);
    }
}

// ---------------- Stage 1: 32x32x16 bf16 MFMA + branchless packed-u32 top-k ---------------
__launch_bounds__(256, 2)
__global__ void score_topk_kernel(const short* __restrict__ Ebf, const short* __restrict__ qbf,
                                  unsigned* __restrict__ parts) {
    // LDS: 2 x panel buffers (64 rows x 33 granules x 16B) = 67584 B.
    // End-merge reuses the whole region: 4 waves x 32 q x 132-u32 stride = 67584 B.
    __shared__ __align__(16) char smem[2 * PANB];

    const int tid  = threadIdx.x;
    const int wave = tid >> 6;
    const int lane = tid & 63;
    const int lh   = lane >> 5;   // k-half
    const int ln   = lane & 31;
    const int mtile = blockIdx.x >> 6;   // 0..7
    const int chunk = blockIdx.x & 63;   // 0..63

    short* buf0 = (short*)smem;
    short* buf1 = (short*)(smem + PANB);

    // A fragments: A[m=lane&31][k=ks*16 + (lane>>5)*8 + j]
    bf16x8 afrag[16];
    {
        const int arow = mtile * QTILE + wave * WQ + ln;
        #pragma unroll
        for (int ks = 0; ks < 16; ks++)
            afrag[ks] = *(const bf16x8*)(qbf + arow * DD + ks * 16 + lh * 8);
    }

    // 16 per-lane 4-deep ascending lists; list r holds q_local=(r&3)+8*(r>>2)+4*lh
    unsigned lst[16][4];
    #pragma unroll
    for (int r = 0; r < 16; r++)
        #pragma unroll
        for (int i = 0; i < 4; i++) lst[r][i] = 0u;

    const int n0c = chunk * CHROWS;

    // prologue: stage panel 0 into buf0 (2048 granules / 256 threads = 8 each)
    bf16x8 st[8];
    #pragma unroll
    for (int it = 0; it < 8; it++) {
        int gi = it * 256 + tid, row = gi >> 5, slot = gi & 31;
        st[it] = *(const bf16x8*)(Ebf + (size_t)(n0c + row) * DD + slot * 8);
    }
    #pragma unroll
    for (int it = 0; it < 8; it++) {
        int gi = it * 256 + tid, row = gi >> 5, slot = gi & 31;
        *(bf16x8*)(buf0 + row * ROWE + slot * 8) = st[it];
    }

    for (int p = 0; p < NPANEL; p++) {
        short* bp = (p & 1) ? buf1 : buf0;
        short* bn = (p & 1) ? buf0 : buf1;
        __syncthreads();
        if (p + 1 < NPANEL) {   // prefetch next panel (overlaps compute)
            const int n1 = n0c + (p + 1) * PANEL;
            #pragma unroll
            for (int it = 0; it < 8; it++) {
                int gi = it * 256 + tid, row = gi >> 5, slot = gi & 31;
                st[it] = *(const bf16x8*)(Ebf + (size_t)(n1 + row) * DD + slot * 8);
            }
        }

        #pragma unroll
        for (int ct = 0; ct < 2; ct++) {   // two 32-col tiles per 64-row panel
            f32x16 acc = {};
            const short* bbase = bp + (ct * 32 + ln) * ROWE + lh * 8;
            #pragma unroll
            for (int ks = 0; ks < 16; ks++) {
                bf16x8 b = *(const bf16x8*)(bbase + ks * 16);   // B[k][n=ln]
                acc = __builtin_amdgcn_mfma_f32_32x32x16_bf16(afrag[ks], b, acc, 0, 0, 0);
            }
            // D: col=lane&31, row=(reg&3)+8*(reg>>2)+4*lh -> one key per owned (q,col)
            const unsigned coln = (unsigned)(p * 64 + ct * 32 + ln);
            #pragma unroll
            for (int r = 0; r < 16; r++) {
                unsigned enc = __float_as_uint(acc[r] + 256.0f);
                unsigned key = (enc & KEYMASK) | coln;
                unsigned n0 = umin(umax(key, lst[r][0]), lst[r][1]);
                unsigned n1 = umin(umax(key, lst[r][1]), lst[r][2]);
                unsigned n2 = umin(umax(key, lst[r][2]), lst[r][3]);
                unsigned n3 = umax(key, lst[r][3]);
                lst[r][0] = n0; lst[r][1] = n1; lst[r][2] = n2; lst[r][3] = n3;
            }
        }

        if (p + 1 < NPANEL) {
            #pragma unroll
            for (int it = 0; it < 8; it++) {
                int gi = it * 256 + tid, row = gi >> 5, slot = gi & 31;
                *(bf16x8*)(bn + row * ROWE + slot * 8) = st[it];
            }
        }
    }

    // ---- end of chunk: per-wave dump (32 q x 128 keys), lanes<32 build top-8 runs ----
    __syncthreads();   // all panel reads complete; reuse whole smem
    unsigned* mw = (unsigned*)smem + (size_t)wave * (WQ * MWS);
    #pragma unroll
    for (int r = 0; r < 16; r++) {
        int q = (r & 3) + 8 * (r >> 2) + 4 * lh;
        u32x4 v; v[0] = lst[r][0]; v[1] = lst[r][1]; v[2] = lst[r][2]; v[3] = lst[r][3];
        *(u32x4*)(mw + q * MWS + ln * 4) = v;   // same-wave LDS, program-order visible
    }
    if (lane < 32) {   // lane = q_local: top-8 of its 128 keys
        unsigned rr[JCH];
        #pragma unroll
        for (int i = 0; i < JCH; i++) rr[i] = 0u;
        #pragma unroll
        for (int j = 0; j < 32; j++) {
            u32x4 v = *(const u32x4*)(mw + lane * MWS + j * 4);
            #pragma unroll
            for (int e = 0; e < 4; e++) {
                unsigned x = v[e];
                unsigned t0 = umin(umax(x, rr[0]), rr[1]);
                unsigned t1 = umin(umax(x, rr[1]), rr[2]);
                unsigned t2 = umin(umax(x, rr[2]), rr[3]);
                unsigned t3 = umin(umax(x, rr[3]), rr[4]);
                unsigned t4 = umin(umax(x, rr[4]), rr[5]);
                unsigned t5 = umin(umax(x, rr[5]), rr[6]);
                unsigned t6 = umin(umax(x, rr[6]), rr[7]);
                unsigned t7 = umax(x, rr[7]);
                rr[0]=t0; rr[1]=t1; rr[2]=t2; rr[3]=t3; rr[4]=t4; rr[5]=t5; rr[6]=t6; rr[7]=t7;
            }
        }
        const int qg = mtile * QTILE + wave * WQ + lane;
        unsigned* dst = parts + ((size_t)qg * NCHUNK + chunk) * JCH;
        #pragma unroll
        for (int i = 0; i < JCH; i++) dst[i] = rr[JCH - 1 - i];   // descending run
    }
}

// ---------------- Stage 2: fused merge (lane=chunk, 20 pops) + exact f32 rescore ----------
__global__ void finalize_kernel(const int* __restrict__ rel, const int* __restrict__ head,
                                const float* __restrict__ E, const float* __restrict__ R,
                                const unsigned* __restrict__ parts, float* __restrict__ out) {
    __shared__ float qv[DD];
    __shared__ int   gl[MSLOT];
    __shared__ float rsc[MSLOT];
    __shared__ int   rgid[MSLOT];

    const int q = blockIdx.x;
    const int tid = threadIdx.x;
    const int wave = tid >> 6, lane = tid & 63;
    const int s1 = q >> 8;

    qv[tid] = E[((size_t)(s1 * PP + head[q])) * DD + tid] * R[(size_t)rel[q] * DD + tid];

    if (wave == 0) {   // lane = chunk; 20 argmax-pops over 64 sorted-desc runs of 8
        unsigned run[JCH];
        const unsigned* src = parts + ((size_t)q * NCHUNK + lane) * JCH;
        #pragma unroll
        for (int j = 0; j < JCH; j++) run[j] = src[j];
        for (int r = 0; r < MSLOT; r++) {
            unsigned best = run[0]; int bl = lane;
            #pragma unroll
            for (int off = 32; off >= 1; off >>= 1) {
                unsigned ob = __shfl_xor(best, off);
                int ol = __shfl_xor(bl, off);
                if (ob > best || (ob == best && ol < bl)) { best = ob; bl = ol; }
            }
            if (lane == bl) {
                int col = (int)(best & 0x7FFu);
                int n = lane * CHROWS + col;
                gl[r] = ((n & (PP - 1)) << 2) | (n >> 15);   // gid = p*4 + s2
                #pragma unroll
                for (int j = 0; j < JCH - 1; j++) run[j] = run[j + 1];
                run[JCH - 1] = 0u;
            }
        }
    }
    __syncthreads();

    // exact f32 rescore: wave w handles candidates w*5 .. w*5+4
    f32x4 qq = *(const f32x4*)(qv + lane * 4);
    #pragma unroll
    for (int c = 0; c < MSLOT / 4; c++) {
        int j = wave * (MSLOT / 4) + c;
        int gid = gl[j];
        int n = (gid & 3) * PP + (gid >> 2);
        f32x4 ev = *(const f32x4*)(E + (size_t)n * DD + lane * 4);
        f32x4 p = qq * ev;
        float s = (p[0] + p[1]) + (p[2] + p[3]);
        #pragma unroll
        for (int off = 32; off >= 1; off >>= 1) s += __shfl_xor(s, off);
        if (lane == 0) { rsc[j] = s; rgid[j] = gid; }
    }
    __syncthreads();

    if (tid < 64) {   // wave 0: 10 argmax-pops over 20 exact scores
        float a = (tid < MSLOT) ? rsc[tid] : -1e30f;
        int   g = (tid < MSLOT) ? rgid[tid] : 0;
        for (int r = 0; r < KTOP; r++) {
            float ps = a; int pg = g; int plm = tid;
            #pragma unroll
            for (int off = 32; off >= 1; off >>= 1) {
                float os = __shfl_xor(ps, off);
                int   og = __shfl_xor(pg, off);
                int   ol = __shfl_xor(plm, off);
                if (os > ps || (os == ps && ol < plm)) { ps = os; pg = og; plm = ol; }
            }
            if (tid == 0) {
                out[q * KTOP + r]             = (float)pg;   // Output 0: gid
                out[QQ * KTOP + q * KTOP + r] = ps;          // Output 1: score
            }
            if (tid == plm) a = -1e30f;
        }
    }
}

extern "C" void kernel_launch(void* const* d_in, const int* in_sizes, int n_in,
                              void* d_out, int out_size, void* d_ws, size_t ws_size,
                              hipStream_t stream) {
    const int*   rel  = (const int*)d_in[0];
    const int*   head = (const int*)d_in[1];
    const float* E    = (const float*)d_in[2];
    const float* R    = (const float*)d_in[3];

    char* ws = (char*)d_ws;
    short* Ebf = (short*)ws;                                   // 67,108,864 B
    short* qbf = (short*)(ws + (size_t)NN * DD * 2);           //    524,288 B
    unsigned* parts = (unsigned*)(ws + (size_t)NN * DD * 2 + (size_t)QQ * DD * 2);   // 2,097,152 B

    prep_kernel<<<dim3(NN * DD / 8 / 256 + QQ), dim3(256), 0, stream>>>(rel, head, E, R, Ebf, qbf);
    score_topk_kernel<<<dim3((QQ / QTILE) * NCHUNK), dim3(256), 0, stream>>>(Ebf, qbf, parts);
    finalize_kernel<<<dim3(QQ), dim3(256), 0, stream>>>(rel, head, E, R, parts, (float*)d_out);
}

// Round 10
// 307.040 us; speedup vs baseline: 12.9835x; 1.0088x over previous
//
#include <hip/hip_runtime.h>

// Dtypes (established round 5): inputs int32/f32, outputs f32 (gid, score).
#define SS 4
#define BB 256
#define PP 32768
#define DD 256
#define QQ 1024          // SS*BB
#define NN 131072        // SS*PP candidate rows
#define KTOP 10
#define QTILE 128        // queries per block (4 waves x 32 q)
#define WQ 32            // q per wave (32x32 MFMA)
#define NCHUNK 64        // n-chunks
#define CHROWS 2048      // rows per chunk
#define PANEL 64         // rows per LDS panel
#define NPANEL (CHROWS / PANEL)   // 32
#define JCH 8            // per-(q,chunk) survivors (sorted desc run)
#define MSLOT 20         // global approx survivors per q (exact-rescored)
#define ROWG 33          // padded LDS row stride in 16B granules
#define ROWE (ROWG * 8)  // row stride in bf16 units (264)
#define PANB (PANEL * ROWG * 16)  // 33792 B per panel buffer
#define KEYMASK 0xFFFFF800u       // keep 21 score bits, low 11 = column
#define MWS 132          // merge-stage row stride in u32 (bank-spread, 16B-aligned)
#define CVB 4096         // convert blocks (32 f32/thread)

typedef __attribute__((ext_vector_type(8))) short bf16x8;
typedef __attribute__((ext_vector_type(4))) float f32x4;
typedef __attribute__((ext_vector_type(16))) float f32x16;
typedef __attribute__((ext_vector_type(4))) unsigned int u32x4;

static __device__ __forceinline__ short f2bf(float f) {   // RNE
    union { float f; unsigned u; } v; v.f = f;
    unsigned r = (v.u + 0x7FFFu + ((v.u >> 16) & 1u)) >> 16;
    return (short)r;
}
static __device__ __forceinline__ bf16x8 cvt8(f32x4 a, f32x4 b) {
    bf16x8 r;
    r[0] = f2bf(a[0]); r[1] = f2bf(a[1]); r[2] = f2bf(a[2]); r[3] = f2bf(a[3]);
    r[4] = f2bf(b[0]); r[5] = f2bf(b[1]); r[6] = f2bf(b[2]); r[7] = f2bf(b[3]);
    return r;
}
static __device__ __forceinline__ unsigned umax(unsigned a, unsigned b) { return a > b ? a : b; }
static __device__ __forceinline__ unsigned umin(unsigned a, unsigned b) { return a < b ? a : b; }

// ---------------- Stage 0: E f32->bf16 (32 elems/thread) AND qvec build ------------------
__global__ void prep_kernel(const int* __restrict__ rel, const int* __restrict__ head,
                            const float* __restrict__ E, const float* __restrict__ R,
                            short* __restrict__ Ebf, short* __restrict__ qbf) {
    if (blockIdx.x < CVB) {
        size_t base = ((size_t)blockIdx.x * 256 + threadIdx.x) * 32;
        #pragma unroll
        for (int c = 0; c < 4; c++) {
            f32x4 a = *(const f32x4*)(E + base + c * 8);
            f32x4 b = *(const f32x4*)(E + base + c * 8 + 4);
            *(bf16x8*)(Ebf + base + c * 8) = cvt8(a, b);
        }
    } else {
        int q = blockIdx.x - CVB, d = threadIdx.x;
        int s1 = q >> 8;
        float f = E[((size_t)(s1 * PP + head[q])) * DD + d] * R[(size_t)rel[q] * DD + d];
        qbf[q * DD + d] = f2bf(f);
    }
}

// ---------------- Stage 1: 32x32x16 bf16 MFMA (dual chains) + packed-u32 top-k ------------
__launch_bounds__(256, 2)
__global__ void score_topk_kernel(const short* __restrict__ Ebf, const short* __restrict__ qbf,
                                  unsigned* __restrict__ parts) {
    // LDS: 2 x panel buffers (64 rows x 33 granules x 16B) = 67584 B.
    // End-merge reuses the region: 4 waves x 32 q x 132-u32 stride = 67584 B.
    __shared__ __align__(16) char smem[2 * PANB];

    const int tid  = threadIdx.x;
    const int wave = tid >> 6;
    const int lane = tid & 63;
    const int lh   = lane >> 5;   // k-half
    const int ln   = lane & 31;
    const int mtile = blockIdx.x >> 6;   // 0..7
    const int chunk = blockIdx.x & 63;   // 0..63

    short* buf0 = (short*)smem;
    short* buf1 = (short*)(smem + PANB);

    // A fragments: A[m=lane&31][k=ks*16 + (lane>>5)*8 + j]
    bf16x8 afrag[16];
    {
        const int arow = mtile * QTILE + wave * WQ + ln;
        #pragma unroll
        for (int ks = 0; ks < 16; ks++)
            afrag[ks] = *(const bf16x8*)(qbf + arow * DD + ks * 16 + lh * 8);
    }

    // 16 per-lane 4-deep ascending lists; list r holds q_local=(r&3)+8*(r>>2)+4*lh
    unsigned lst[16][4];
    #pragma unroll
    for (int r = 0; r < 16; r++)
        #pragma unroll
        for (int i = 0; i < 4; i++) lst[r][i] = 0u;

    const int n0c = chunk * CHROWS;

    // prologue: stage panel 0 into buf0 (2048 granules / 256 threads = 8 each)
    bf16x8 st[8];
    #pragma unroll
    for (int it = 0; it < 8; it++) {
        int gi = it * 256 + tid, row = gi >> 5, slot = gi & 31;
        st[it] = *(const bf16x8*)(Ebf + (size_t)(n0c + row) * DD + slot * 8);
    }
    #pragma unroll
    for (int it = 0; it < 8; it++) {
        int gi = it * 256 + tid, row = gi >> 5, slot = gi & 31;
        *(bf16x8*)(buf0 + row * ROWE + slot * 8) = st[it];
    }

    for (int p = 0; p < NPANEL; p++) {
        short* bp = (p & 1) ? buf1 : buf0;
        short* bn = (p & 1) ? buf0 : buf1;
        __syncthreads();
        if (p + 1 < NPANEL) {   // prefetch next panel (overlaps compute)
            const int n1 = n0c + (p + 1) * PANEL;
            #pragma unroll
            for (int it = 0; it < 8; it++) {
                int gi = it * 256 + tid, row = gi >> 5, slot = gi & 31;
                st[it] = *(const bf16x8*)(Ebf + (size_t)(n1 + row) * DD + slot * 8);
            }
        }

        // two independent accumulator chains (cols ln and 32+ln), bias folded into C init
        f32x16 acc0, acc1;
        #pragma unroll
        for (int r = 0; r < 16; r++) { acc0[r] = 256.0f; acc1[r] = 256.0f; }
        const short* b0 = bp + ln * ROWE + lh * 8;
        const short* b1 = bp + (32 + ln) * ROWE + lh * 8;
        #pragma unroll
        for (int ks = 0; ks < 16; ks++) {
            bf16x8 x0 = *(const bf16x8*)(b0 + ks * 16);
            bf16x8 x1 = *(const bf16x8*)(b1 + ks * 16);
            acc0 = __builtin_amdgcn_mfma_f32_32x32x16_bf16(afrag[ks], x0, acc0, 0, 0, 0);
            acc1 = __builtin_amdgcn_mfma_f32_32x32x16_bf16(afrag[ks], x1, acc1, 0, 0, 0);
        }

        // D: col=lane&31, row=(reg&3)+8*(reg>>2)+4*lh -> one key per owned (q,col)
        const unsigned c0 = (unsigned)(p * 64 + ln);
        const unsigned c1 = (unsigned)(p * 64 + 32 + ln);
        #pragma unroll
        for (int r = 0; r < 16; r++) {
            unsigned key = (__float_as_uint(acc0[r]) & KEYMASK) | c0;
            unsigned n0 = umin(umax(key, lst[r][0]), lst[r][1]);
            unsigned n1 = umin(umax(key, lst[r][1]), lst[r][2]);
            unsigned n2 = umin(umax(key, lst[r][2]), lst[r][3]);
            unsigned n3 = umax(key, lst[r][3]);
            lst[r][0] = n0; lst[r][1] = n1; lst[r][2] = n2; lst[r][3] = n3;
        }
        #pragma unroll
        for (int r = 0; r < 16; r++) {
            unsigned key = (__float_as_uint(acc1[r]) & KEYMASK) | c1;
            unsigned n0 = umin(umax(key, lst[r][0]), lst[r][1]);
            unsigned n1 = umin(umax(key, lst[r][1]), lst[r][2]);
            unsigned n2 = umin(umax(key, lst[r][2]), lst[r][3]);
            unsigned n3 = umax(key, lst[r][3]);
            lst[r][0] = n0; lst[r][1] = n1; lst[r][2] = n2; lst[r][3] = n3;
        }

        if (p + 1 < NPANEL) {
            #pragma unroll
            for (int it = 0; it < 8; it++) {
                int gi = it * 256 + tid, row = gi >> 5, slot = gi & 31;
                *(bf16x8*)(bn + row * ROWE + slot * 8) = st[it];
            }
        }
    }

    // ---- end of chunk: per-wave dump (32 q x 128 keys), lanes<32 build top-8 runs ----
    __syncthreads();   // all panel reads complete; reuse whole smem
    unsigned* mw = (unsigned*)smem + (size_t)wave * (WQ * MWS);
    #pragma unroll
    for (int r = 0; r < 16; r++) {
        int q = (r & 3) + 8 * (r >> 2) + 4 * lh;
        u32x4 v; v[0] = lst[r][0]; v[1] = lst[r][1]; v[2] = lst[r][2]; v[3] = lst[r][3];
        *(u32x4*)(mw + q * MWS + ln * 4) = v;   // same-wave LDS, program-order visible
    }
    if (lane < 32) {   // lane = q_local: top-8 of its 128 keys
        unsigned rr[JCH];
        #pragma unroll
        for (int i = 0; i < JCH; i++) rr[i] = 0u;
        #pragma unroll
        for (int j = 0; j < 32; j++) {
            u32x4 v = *(const u32x4*)(mw + lane * MWS + j * 4);
            #pragma unroll
            for (int e = 0; e < 4; e++) {
                unsigned x = v[e];
                unsigned t0 = umin(umax(x, rr[0]), rr[1]);
                unsigned t1 = umin(umax(x, rr[1]), rr[2]);
                unsigned t2 = umin(umax(x, rr[2]), rr[3]);
                unsigned t3 = umin(umax(x, rr[3]), rr[4]);
                unsigned t4 = umin(umax(x, rr[4]), rr[5]);
                unsigned t5 = umin(umax(x, rr[5]), rr[6]);
                unsigned t6 = umin(umax(x, rr[6]), rr[7]);
                unsigned t7 = umax(x, rr[7]);
                rr[0]=t0; rr[1]=t1; rr[2]=t2; rr[3]=t3; rr[4]=t4; rr[5]=t5; rr[6]=t6; rr[7]=t7;
            }
        }
        const int qg = mtile * QTILE + wave * WQ + lane;
        unsigned* dst = parts + ((size_t)qg * NCHUNK + chunk) * JCH;
        #pragma unroll
        for (int i = 0; i < JCH; i++) dst[i] = rr[JCH - 1 - i];   // descending run
    }
}

// ---------------- Stage 2: fused merge (lane=chunk, 20 pops) + exact f32 rescore ----------
__global__ void finalize_kernel(const int* __restrict__ rel, const int* __restrict__ head,
                                const float* __restrict__ E, const float* __restrict__ R,
                                const unsigned* __restrict__ parts, float* __restrict__ out) {
    __shared__ float qv[DD];
    __shared__ int   gl[MSLOT];
    __shared__ float rsc[MSLOT];
    __shared__ int   rgid[MSLOT];

    const int q = blockIdx.x;
    const int tid = threadIdx.x;
    const int wave = tid >> 6, lane = tid & 63;
    const int s1 = q >> 8;

    qv[tid] = E[((size_t)(s1 * PP + head[q])) * DD + tid] * R[(size_t)rel[q] * DD + tid];

    if (wave == 0) {   // lane = chunk; 20 argmax-pops over 64 sorted-desc runs of 8
        unsigned run[JCH];
        const unsigned* src = parts + ((size_t)q * NCHUNK + lane) * JCH;
        #pragma unroll
        for (int j = 0; j < JCH; j++) run[j] = src[j];
        for (int r = 0; r < MSLOT; r++) {
            unsigned best = run[0]; int bl = lane;
            #pragma unroll
            for (int off = 32; off >= 1; off >>= 1) {
                unsigned ob = __shfl_xor(best, off);
                int ol = __shfl_xor(bl, off);
                if (ob > best || (ob == best && ol < bl)) { best = ob; bl = ol; }
            }
            if (lane == bl) {
                int col = (int)(best & 0x7FFu);
                int n = lane * CHROWS + col;
                gl[r] = ((n & (PP - 1)) << 2) | (n >> 15);   // gid = p*4 + s2
                #pragma unroll
                for (int j = 0; j < JCH - 1; j++) run[j] = run[j + 1];
                run[JCH - 1] = 0u;
            }
        }
    }
    __syncthreads();

    // exact f32 rescore: wave w handles candidates w*5 .. w*5+4
    f32x4 qq = *(const f32x4*)(qv + lane * 4);
    #pragma unroll
    for (int c = 0; c < MSLOT / 4; c++) {
        int j = wave * (MSLOT / 4) + c;
        int gid = gl[j];
        int n = (gid & 3) * PP + (gid >> 2);
        f32x4 ev = *(const f32x4*)(E + (size_t)n * DD + lane * 4);
        f32x4 p = qq * ev;
        float s = (p[0] + p[1]) + (p[2] + p[3]);
        #pragma unroll
        for (int off = 32; off >= 1; off >>= 1) s += __shfl_xor(s, off);
        if (lane == 0) { rsc[j] = s; rgid[j] = gid; }
    }
    __syncthreads();

    if (tid < 64) {   // wave 0: 10 argmax-pops over 20 exact scores
        float a = (tid < MSLOT) ? rsc[tid] : -1e30f;
        int   g = (tid < MSLOT) ? rgid[tid] : 0;
        for (int r = 0; r < KTOP; r++) {
            float ps = a; int pg = g; int plm = tid;
            #pragma unroll
            for (int off = 32; off >= 1; off >>= 1) {
                float os = __shfl_xor(ps, off);
                int   og = __shfl_xor(pg, off);
                int   ol = __shfl_xor(plm, off);
                if (os > ps || (os == ps && ol < plm)) { ps = os; pg = og; plm = ol; }
            }
            if (tid == 0) {
                out[q * KTOP + r]             = (float)pg;   // Output 0: gid
                out[QQ * KTOP + q * KTOP + r] = ps;          // Output 1: score
            }
            if (tid == plm) a = -1e30f;
        }
    }
}

extern "C" void kernel_launch(void* const* d_in, const int* in_sizes, int n_in,
                              void* d_out, int out_size, void* d_ws, size_t ws_size,
                              hipStream_t stream) {
    const int*   rel  = (const int*)d_in[0];
    const int*   head = (const int*)d_in[1];
    const float* E    = (const float*)d_in[2];
    const float* R    = (const float*)d_in[3];

    char* ws = (char*)d_ws;
    short* Ebf = (short*)ws;                                   // 67,108,864 B
    short* qbf = (short*)(ws + (size_t)NN * DD * 2);           //    524,288 B
    unsigned* parts = (unsigned*)(ws + (size_t)NN * DD * 2 + (size_t)QQ * DD * 2);   // 2,097,152 B

    prep_kernel<<<dim3(CVB + QQ), dim3(256), 0, stream>>>(rel, head, E, R, Ebf, qbf);
    score_topk_kernel<<<dim3((QQ / QTILE) * NCHUNK), dim3(256), 0, stream>>>(Ebf, qbf, parts);
    finalize_kernel<<<dim3(QQ), dim3(256), 0, stream>>>(rel, head, E, R, parts, (float*)d_out);
}